// Round 5
// baseline (83.592 us; speedup 1.0000x reference)
//
#include <hip/hip_runtime.h>
#include <stdint.h>

#define NUM_CLASS 10000
#define FEATDIM   512
#define BATCH     4096
#define MROWS     8192            // soft rows 0..4095, hard rows 4096..8191
#define BM        128
#define BN        128
#define KSTEPS    4               // K=512 in 4 steps of 128
#define NTILES    79              // ceil(10000/128)
#define NSPLIT    12              // 12*64 = 768 blocks = 3/CU exact
#define ROWTILES  64
#define WPAD_ROWS 10112           // 79*128
#define ROWB4     256             // fp4 bytes per row (512 elems * 4 bit)
#define KBLKS     16              // 32-elem scale blocks per row

// prep kernel block ranges (256 threads each)
#define PB_CVTX   512             // 8192*16 = 131072 block-quant threads
#define PB_CVTW   632             // 10112*16 = 161792
#define PB_ROWS   1024            // 4096 rows, 4/block
#define PB_ZERO   8               // zero sumexp (8192 f32)
#define PB_TOTAL  (PB_CVTX + PB_CVTW + PB_ROWS + PB_ZERO)

typedef float f32x4 __attribute__((ext_vector_type(4)));
typedef int   i32x8 __attribute__((ext_vector_type(8)));

__device__ __forceinline__ void gll16(const void* g, void* l) {
  __builtin_amdgcn_global_load_lds(
      (const __attribute__((address_space(1))) void*)g,
      (__attribute__((address_space(3))) void*)l,
      16, 0, 0);
}

// ---- fp4 e2m1 quantization: code grid {0,.5,1,1.5,2,3,4,6} ----
__device__ __forceinline__ unsigned q1(float v, float rs) {
  float a = fabsf(v) * rs;
  unsigned s = (__float_as_uint(v) >> 31) << 3;
  unsigned c = a < 0.25f ? 0u : a < 0.75f ? 1u : a < 1.25f ? 2u : a < 1.75f ? 3u
             : a < 2.5f  ? 4u : a < 3.5f  ? 5u : a < 5.0f  ? 6u : 7u;
  return s | c;
}

// quantize one 32-elem block (8 float4) -> 16 fp4 bytes + E8M0 scale byte
__device__ __forceinline__ void quant32(const float4* __restrict__ src,
                                        uint4* __restrict__ dst,
                                        unsigned char* __restrict__ sdst) {
  float4 v[8];
#pragma unroll
  for (int i = 0; i < 8; ++i) v[i] = src[i];
  float m = 0.f;
#pragma unroll
  for (int i = 0; i < 8; ++i) {
    m = fmaxf(m, fmaxf(fmaxf(fabsf(v[i].x), fabsf(v[i].y)),
                       fmaxf(fabsf(v[i].z), fabsf(v[i].w))));
  }
  unsigned sb; float rs;
  if (m == 0.f) { sb = 0u; rs = 0.f; }
  else {
    int e = (int)ceilf(log2f(m * 0.16666667f) - 1e-6f);   // 2^e >= m/6
    e = e < -126 ? -126 : (e > 127 ? 127 : e);
    sb = (unsigned)(e + 127);
    rs = __uint_as_float((unsigned)(127 - e) << 23);      // 2^-e
  }
  unsigned wd[4] = {0u, 0u, 0u, 0u};
#pragma unroll
  for (int i = 0; i < 8; ++i) {
    unsigned hw = q1(v[i].x, rs) | (q1(v[i].y, rs) << 4) |
                  (q1(v[i].z, rs) << 8) | (q1(v[i].w, rs) << 12);
    wd[i >> 1] |= hw << ((i & 1) * 16);
  }
  uint4 o = {wd[0], wd[1], wd[2], wd[3]};
  *dst = o;
  *sdst = (unsigned char)sb;
}

// ---- fused prep: quant X->fp4, quant W->fp4, per-row stats, zero sumexp ----
__global__ void prep_kernel(const float* __restrict__ sx, const float* __restrict__ hx,
                            const int* __restrict__ tgt,
                            const float* __restrict__ centers,
                            const float* __restrict__ weight,
                            uint4* __restrict__ X4, uint4* __restrict__ W4,
                            unsigned char* __restrict__ SX, unsigned char* __restrict__ SW,
                            float* __restrict__ tlogit, float* __restrict__ qrow,
                            float4* __restrict__ sumexp4) {
  const int b   = blockIdx.x;
  const int tid = threadIdx.x;

  if (b < PB_CVTX) {
    int idx = b * 256 + tid;                 // (row, k-block)
    int row = idx >> 4, blk = idx & 15;
    const float* base = (row < BATCH) ? sx : hx;
    int r = (row < BATCH) ? row : row - BATCH;
    const float4* src = (const float4*)(base + (size_t)r * FEATDIM) + blk * 8;
    quant32(src, &X4[idx], &SX[idx]);
    return;
  }
  if (b < PB_CVTX + PB_CVTW) {
    int idx = (b - PB_CVTX) * 256 + tid;
    int row = idx >> 4, blk = idx & 15;
    if (row < NUM_CLASS) {
      const float4* src = (const float4*)(weight + (size_t)row * FEATDIM) + blk * 8;
      quant32(src, &W4[idx], &SW[idx]);
    } else {
      uint4 z = {0u, 0u, 0u, 0u};
      W4[idx] = z;
      SW[idx] = 0;
    }
    return;
  }
  if (b < PB_CVTX + PB_CVTW + PB_ROWS) {
    // per-row: target logits (f32 exact) + quantization sum
    int row  = (b - PB_CVTX - PB_CVTW) * 4 + (tid >> 6);
    int lane = tid & 63;
    int t = tgt[row];
    const float4* s4 = (const float4*)(sx + (size_t)row * FEATDIM);
    const float4* h4 = (const float4*)(hx + (size_t)row * FEATDIM);
    const float4* c4 = (const float4*)(centers + (size_t)t * FEATDIM);
    const float4* w4 = (const float4*)(weight + (size_t)t * FEATDIM);
    float qs = 0.f, ds = 0.f, dh = 0.f;
#pragma unroll
    for (int j = 0; j < 2; ++j) {
      int i = lane + j * 64;
      float4 s = s4[i], h = h4[i], c = c4[i], w = w4[i];
      float d0 = s.x - c.x, d1 = s.y - c.y, d2 = s.z - c.z, d3 = s.w - c.w;
      float e0 = h.x - c.x, e1 = h.y - c.y, e2 = h.z - c.z, e3 = h.w - c.w;
      qs += d0*d0 + d1*d1 + d2*d2 + d3*d3 + e0*e0 + e1*e1 + e2*e2 + e3*e3;
      ds += s.x*w.x + s.y*w.y + s.z*w.z + s.w*w.w;
      dh += h.x*w.x + h.y*w.y + h.z*w.z + h.w*w.w;
    }
#pragma unroll
    for (int m = 1; m < 64; m <<= 1) {
      qs += __shfl_xor(qs, m);
      ds += __shfl_xor(ds, m);
      dh += __shfl_xor(dh, m);
    }
    if (lane == 0) {
      tlogit[row]         = ds;
      tlogit[BATCH + row] = dh;
      qrow[row]           = qs;
    }
    return;
  }
  {
    int idx = (b - PB_CVTX - PB_CVTW - PB_ROWS) * 256 + tid;
    float4 z = {0.f, 0.f, 0.f, 0.f};
    sumexp4[idx] = z;
  }
}

__device__ __forceinline__ i32x8 mk8(uint4 q) {
  i32x8 v;
  v[0] = (int)q.x; v[1] = (int)q.y; v[2] = (int)q.z; v[3] = (int)q.w;
  v[4] = 0; v[5] = 0; v[6] = 0; v[7] = 0;
  return v;
}

// ---- fused MX-fp4 GEMM + sum-of-exp, 2-phase double-buffered LDS ----
// LDS tile layout (row r of 128, byte c of 64 per K-step):
//   lds[r*64 + (c ^ (((r>>1)&3)<<4))]
// Quarter-wave bank check: lanes rl=0..15 at fixed h read addr bits4-6 =
// (rl&1, h^((rl>>1)&3)) -> 8 slots x 2 lanes = conflict-free.
__launch_bounds__(256, 3)
__global__ void gemm_lse_kernel(const char* __restrict__ X4, const char* __restrict__ W4,
                                const unsigned char* __restrict__ SX,
                                const unsigned char* __restrict__ SW,
                                float* __restrict__ sumexp) {
  __shared__ char ldsA[2][BM * 64];   // 8 KB per buffer
  __shared__ char ldsB[2][BN * 64];

  const int tid  = threadIdx.x;
  const int lane = tid & 63;
  const int w    = tid >> 6;
  const int wm   = w >> 1;          // 2x2 wave grid, each wave 64x64
  const int wn   = w & 1;
  const int chunk   = blockIdx.x >> 6;
  const int rowtile = blockIdx.x & 63;
  const int nt0 = (chunk * NTILES) / NSPLIT;
  const int nt1 = ((chunk + 1) * NTILES) / NSPLIT;
  const int G   = (nt1 - nt0) * KSTEPS;

  // staging: 8 segs of 1KB per matrix per step; wave w stages segs {2w,2w+1}.
  // dest linear lane*16; source col = ((lane&3)^((lane>>3)&3))<<4 (inverse swz).
  const int scol = (((lane & 3) ^ ((lane >> 3) & 3)) << 4);
  int srow[2], sdst[2];
#pragma unroll
  for (int j = 0; j < 2; ++j) {
    int seg = w * 2 + j;
    srow[j] = seg * 16 + (lane >> 2);
    sdst[j] = seg * 1024 + lane * 16;
  }

  const int arow0 = rowtile * BM;
  const int rl = lane & 15;
  const int h  = lane >> 4;
  const int rcol = ((h ^ ((rl >> 1) & 3)) << 4);   // frag read col (swizzled)

  float se[4][4];
#pragma unroll
  for (int mi = 0; mi < 4; ++mi)
#pragma unroll
    for (int r = 0; r < 4; ++r) se[mi][r] = 0.f;

  f32x4 acc[4][4];

  // prologue: stage g=0 into buffer 0
  {
    const int brow0 = nt0 * BN;
#pragma unroll
    for (int j = 0; j < 2; ++j) {
      gll16(X4 + (size_t)(arow0 + srow[j]) * ROWB4 + scol, ldsA[0] + sdst[j]);
      gll16(W4 + (size_t)(brow0 + srow[j]) * ROWB4 + scol, ldsB[0] + sdst[j]);
    }
  }
  __syncthreads();

  for (int g = 0; g < G; ++g) {
    const int p  = g & 1;
    const int ks = g & 3;
    const int nt = nt0 + (g >> 2);
    const int brow0 = nt * BN;

    // stage g+1 into the other buffer (overlaps with MFMA below)
    if (g + 1 < G) {
      const int ks2 = (g + 1) & 3;
      const int brow2 = (nt0 + ((g + 1) >> 2)) * BN;
#pragma unroll
      for (int j = 0; j < 2; ++j) {
        gll16(X4 + (size_t)(arow0 + srow[j]) * ROWB4 + ks2 * 64 + scol,
              ldsA[p ^ 1] + sdst[j]);
        gll16(W4 + (size_t)(brow2 + srow[j]) * ROWB4 + ks2 * 64 + scol,
              ldsB[p ^ 1] + sdst[j]);
      }
    }

    // per-lane E8M0 scale bytes (lane owns exactly one 32-block)
    int sa[4], sb[4];
#pragma unroll
    for (int mi = 0; mi < 4; ++mi)
      sa[mi] = (int)(SX[(size_t)(arow0 + wm * 64 + mi * 16 + rl) * KBLKS + ks * 4 + h]
                     * 0x01010101u);
#pragma unroll
    for (int ni = 0; ni < 4; ++ni)
      sb[ni] = (int)(SW[(size_t)(brow0 + wn * 64 + ni * 16 + rl) * KBLKS + ks * 4 + h]
                     * 0x01010101u);

    if (ks == 0) {
#pragma unroll
      for (int mi = 0; mi < 4; ++mi)
#pragma unroll
        for (int ni = 0; ni < 4; ++ni) {
          f32x4 z = {0.f, 0.f, 0.f, 0.f};
          acc[mi][ni] = z;
        }
    }

    uint4 aq[4], bq[4];
#pragma unroll
    for (int mi = 0; mi < 4; ++mi)
      aq[mi] = *(const uint4*)(ldsA[p] + (wm * 64 + mi * 16 + rl) * 64 + rcol);
#pragma unroll
    for (int ni = 0; ni < 4; ++ni)
      bq[ni] = *(const uint4*)(ldsB[p] + (wn * 64 + ni * 16 + rl) * 64 + rcol);

    i32x8 bv[4];
#pragma unroll
    for (int ni = 0; ni < 4; ++ni) bv[ni] = mk8(bq[ni]);
#pragma unroll
    for (int mi = 0; mi < 4; ++mi) {
      i32x8 av = mk8(aq[mi]);
#pragma unroll
      for (int ni = 0; ni < 4; ++ni)
        acc[mi][ni] = __builtin_amdgcn_mfma_scale_f32_16x16x128_f8f6f4(
            av, bv[ni], acc[mi][ni],
            4, 4,                      // cbsz=FP4(A), blgp=FP4(B)
            0, sa[mi], 0, sb[ni]);
    }

    __syncthreads();   // drains vmcnt(0)+lgkmcnt(0): stage g+1 done, reads done

    if (ks == 3) {
      // epilogue: sum exp over this 128-col tile (register-only, overlaps
      // other waves' next-step work); mask ragged cols >= NUM_CLASS
      const int colb = nt * BN + wn * 64 + rl;
#pragma unroll
      for (int ni = 0; ni < 4; ++ni) {
        bool ok = (colb + ni * 16) < NUM_CLASS;
#pragma unroll
        for (int mi = 0; mi < 4; ++mi)
#pragma unroll
          for (int r = 0; r < 4; ++r)
            if (ok) se[mi][r] += __expf(acc[mi][ni][r]);
      }
    }
  }

  // C/D layout: col = lane&15 (summed over), row = (lane>>4)*4 + r
#pragma unroll
  for (int m = 1; m < 16; m <<= 1)
#pragma unroll
    for (int mi = 0; mi < 4; ++mi)
#pragma unroll
      for (int r = 0; r < 4; ++r)
        se[mi][r] += __shfl_xor(se[mi][r], m);

  if ((lane & 15) == 0) {
#pragma unroll
    for (int mi = 0; mi < 4; ++mi)
#pragma unroll
      for (int r = 0; r < 4; ++r) {
        int grow = arow0 + wm * 64 + mi * 16 + ((lane >> 4) << 2) + r;
        atomicAdd(&sumexp[grow], se[mi][r]);
      }
  }
}

// ---- final scalar reduction ----
__global__ void finalize_kernel(const float* __restrict__ sumexp,
                                const float* __restrict__ tlogit,
                                const float* __restrict__ qrow,
                                float* __restrict__ out) {
  int tid = threadIdx.x;     // 1024 threads
  float acc = 0.f, q = 0.f;
  for (int i = tid; i < MROWS; i += 1024)
    acc += logf(sumexp[i]) - tlogit[i];
  for (int i = tid; i < BATCH; i += 1024)
    q += qrow[i];
#pragma unroll
  for (int m = 1; m < 64; m <<= 1) {
    acc += __shfl_xor(acc, m);
    q   += __shfl_xor(q, m);
  }
  __shared__ float redA[16], redQ[16];
  if ((tid & 63) == 0) { redA[tid >> 6] = acc; redQ[tid >> 6] = q; }
  __syncthreads();
  if (tid == 0) {
    float s = 0.f, qq = 0.f;
#pragma unroll
    for (int i = 0; i < 16; ++i) { s += redA[i]; qq += redQ[i]; }
    // loss = (ce1_sum + ce2_sum)/B + PARAM * 0.5 * qsum / B ; PARAM=0.5, B=4096
    out[0] = s * (1.0f / BATCH) + qq * (1.0f / 16384.0f);
  }
}

extern "C" void kernel_launch(void* const* d_in, const int* in_sizes, int n_in,
                              void* d_out, int out_size, void* d_ws, size_t ws_size,
                              hipStream_t stream) {
  const float* sx = (const float*)d_in[0];
  const float* hx = (const float*)d_in[1];
  const int*   tg = (const int*)d_in[2];
  const float* ct = (const float*)d_in[3];
  const float* wt = (const float*)d_in[4];
  float* out = (float*)d_out;

  char* ws = (char*)d_ws;
  char* X4 = ws;                                                // 2,097,152 B
  char* W4 = X4 + (size_t)MROWS * ROWB4;                        // 2,588,672 B
  unsigned char* SX = (unsigned char*)(W4 + (size_t)WPAD_ROWS * ROWB4); // 131,072 B
  unsigned char* SW = SX + (size_t)MROWS * KBLKS;               // 161,792 B
  char* tail = (char*)(SW + (size_t)WPAD_ROWS * KBLKS);
  float* sumexp = (float*)tail;                                 // 8192 f32
  float* tlogit = (float*)(tail + (size_t)MROWS * 4);           // 8192 f32
  float* qrow   = (float*)(tail + (size_t)MROWS * 8);           // 4096 f32

  prep_kernel<<<PB_TOTAL, 256, 0, stream>>>(sx, hx, tg, ct, wt,
                                            (uint4*)X4, (uint4*)W4, SX, SW,
                                            tlogit, qrow, (float4*)sumexp);
  gemm_lse_kernel<<<NSPLIT * ROWTILES, 256, 0, stream>>>(X4, W4, SX, SW, sumexp);
  finalize_kernel<<<1, 1024, 0, stream>>>(sumexp, tlogit, qrow, out);
}

// Round 6
// 61.071 us; speedup vs baseline: 1.3688x; 1.3688x over previous
//
#include <hip/hip_runtime.h>
#include <stdint.h>

#define NUM_CLASS 10000
#define FEATDIM   512
#define BATCH     4096
#define MROWS     8192            // soft rows 0..4095, hard rows 4096..8191
#define BM        128
#define BN        128
#define NTILES    79              // ceil(10000/128)
#define NSPLIT    12              // 12*64 = 768 blocks = 3/CU exact
#define ROWTILES  64
#define WPAD_ROWS 10112           // 79*128
#define ROWB4     256             // fp4 bytes per row (512 elems * 4 bit)
#define KBLKS     16              // 32-elem scale blocks per row

// prep kernel block ranges (256 threads each)
#define PB_CVTX   512             // 8192*16 = 131072 block-quant threads
#define PB_CVTW   632             // 10112*16 = 161792
#define PB_ROWS   1024            // 4096 rows, 4/block
#define PB_ZERO   8               // zero sumexp (8192 f32)
#define PB_TOTAL  (PB_CVTX + PB_CVTW + PB_ROWS + PB_ZERO)

typedef float f32x4 __attribute__((ext_vector_type(4)));
typedef int   i32x8 __attribute__((ext_vector_type(8)));

__device__ __forceinline__ void gll16(const void* g, void* l) {
  __builtin_amdgcn_global_load_lds(
      (const __attribute__((address_space(1))) void*)g,
      (__attribute__((address_space(3))) void*)l,
      16, 0, 0);
}

// ---- fp4 e2m1 quantization: code grid {0,.5,1,1.5,2,3,4,6} ----
__device__ __forceinline__ unsigned q1(float v, float rs) {
  float a = fabsf(v) * rs;
  unsigned s = (__float_as_uint(v) >> 31) << 3;
  unsigned c = a < 0.25f ? 0u : a < 0.75f ? 1u : a < 1.25f ? 2u : a < 1.75f ? 3u
             : a < 2.5f  ? 4u : a < 3.5f  ? 5u : a < 5.0f  ? 6u : 7u;
  return s | c;
}

// quantize one 32-elem block (8 float4) -> 16 fp4 bytes + E8M0 scale byte
__device__ __forceinline__ void quant32(const float4* __restrict__ src,
                                        uint4* __restrict__ dst,
                                        unsigned char* __restrict__ sdst) {
  float4 v[8];
#pragma unroll
  for (int i = 0; i < 8; ++i) v[i] = src[i];
  float m = 0.f;
#pragma unroll
  for (int i = 0; i < 8; ++i) {
    m = fmaxf(m, fmaxf(fmaxf(fabsf(v[i].x), fabsf(v[i].y)),
                       fmaxf(fabsf(v[i].z), fabsf(v[i].w))));
  }
  unsigned sb; float rs;
  if (m == 0.f) { sb = 0u; rs = 0.f; }
  else {
    int e = (int)ceilf(log2f(m * 0.16666667f) - 1e-6f);   // 2^e >= m/6
    e = e < -126 ? -126 : (e > 127 ? 127 : e);
    sb = (unsigned)(e + 127);
    rs = __uint_as_float((unsigned)(127 - e) << 23);      // 2^-e
  }
  unsigned wd[4] = {0u, 0u, 0u, 0u};
#pragma unroll
  for (int i = 0; i < 8; ++i) {
    unsigned hw = q1(v[i].x, rs) | (q1(v[i].y, rs) << 4) |
                  (q1(v[i].z, rs) << 8) | (q1(v[i].w, rs) << 12);
    wd[i >> 1] |= hw << ((i & 1) * 16);
  }
  uint4 o = {wd[0], wd[1], wd[2], wd[3]};
  *dst = o;
  *sdst = (unsigned char)sb;
}

// scale repack position: k-block b (elems [32b,32b+32)) -> row*16 + (b&3)*4 + (b>>2)
// so a uint load at row*16 + h*4 yields scales for ks=0..3 in bytes 0..3.
__device__ __forceinline__ int spos(int row, int blk) {
  return row * 16 + (blk & 3) * 4 + (blk >> 2);
}

// ---- fused prep: quant X->fp4, quant W->fp4, per-row stats, zero sumexp ----
__global__ void prep_kernel(const float* __restrict__ sx, const float* __restrict__ hx,
                            const int* __restrict__ tgt,
                            const float* __restrict__ centers,
                            const float* __restrict__ weight,
                            uint4* __restrict__ X4, uint4* __restrict__ W4,
                            unsigned char* __restrict__ SX, unsigned char* __restrict__ SW,
                            float* __restrict__ tlogit, float* __restrict__ qrow,
                            float4* __restrict__ sumexp4) {
  const int b   = blockIdx.x;
  const int tid = threadIdx.x;

  if (b < PB_CVTX) {
    int idx = b * 256 + tid;                 // (row, k-block)
    int row = idx >> 4, blk = idx & 15;
    const float* base = (row < BATCH) ? sx : hx;
    int r = (row < BATCH) ? row : row - BATCH;
    const float4* src = (const float4*)(base + (size_t)r * FEATDIM) + blk * 8;
    quant32(src, &X4[idx], &SX[spos(row, blk)]);
    return;
  }
  if (b < PB_CVTX + PB_CVTW) {
    int idx = (b - PB_CVTX) * 256 + tid;
    int row = idx >> 4, blk = idx & 15;
    if (row < NUM_CLASS) {
      const float4* src = (const float4*)(weight + (size_t)row * FEATDIM) + blk * 8;
      quant32(src, &W4[idx], &SW[spos(row, blk)]);
    } else {
      uint4 z = {0u, 0u, 0u, 0u};
      W4[idx] = z;
      SW[spos(row, blk)] = 0;
    }
    return;
  }
  if (b < PB_CVTX + PB_CVTW + PB_ROWS) {
    // per-row: target logits (f32 exact) + quantization sum
    int row  = (b - PB_CVTX - PB_CVTW) * 4 + (tid >> 6);
    int lane = tid & 63;
    int t = tgt[row];
    const float4* s4 = (const float4*)(sx + (size_t)row * FEATDIM);
    const float4* h4 = (const float4*)(hx + (size_t)row * FEATDIM);
    const float4* c4 = (const float4*)(centers + (size_t)t * FEATDIM);
    const float4* w4 = (const float4*)(weight + (size_t)t * FEATDIM);
    float qs = 0.f, ds = 0.f, dh = 0.f;
#pragma unroll
    for (int j = 0; j < 2; ++j) {
      int i = lane + j * 64;
      float4 s = s4[i], h = h4[i], c = c4[i], w = w4[i];
      float d0 = s.x - c.x, d1 = s.y - c.y, d2 = s.z - c.z, d3 = s.w - c.w;
      float e0 = h.x - c.x, e1 = h.y - c.y, e2 = h.z - c.z, e3 = h.w - c.w;
      qs += d0*d0 + d1*d1 + d2*d2 + d3*d3 + e0*e0 + e1*e1 + e2*e2 + e3*e3;
      ds += s.x*w.x + s.y*w.y + s.z*w.z + s.w*w.w;
      dh += h.x*w.x + h.y*w.y + h.z*w.z + h.w*w.w;
    }
#pragma unroll
    for (int m = 1; m < 64; m <<= 1) {
      qs += __shfl_xor(qs, m);
      ds += __shfl_xor(ds, m);
      dh += __shfl_xor(dh, m);
    }
    if (lane == 0) {
      tlogit[row]         = ds;
      tlogit[BATCH + row] = dh;
      qrow[row]           = qs;
    }
    return;
  }
  {
    int idx = (b - PB_CVTX - PB_CVTW - PB_ROWS) * 256 + tid;
    float4 z = {0.f, 0.f, 0.f, 0.f};
    sumexp4[idx] = z;
  }
}

__device__ __forceinline__ i32x8 mk8(uint4 q) {
  i32x8 v;
  v[0] = (int)q.x; v[1] = (int)q.y; v[2] = (int)q.z; v[3] = (int)q.w;
  v[4] = 0; v[5] = 0; v[6] = 0; v[7] = 0;
  return v;
}

// ---- fused MX-fp4 GEMM + sum-of-exp ----
// Single-buffered 32KB LDS, K=256 per phase (2 sub-tiles of [128 rows][64B]).
// Sub-tile swizzle (verified zero-conflict in R5): read col = ((h^((rl>>1)&3))<<4),
// stage source col = (((lane&3)^((lane>>3)&3))<<4), dest linear lane*16.
// Scales: A-scales preloaded per block (4 uint), B-scales per nt (4 uint),
// repacked so one uint = scales for ks=0..3.
__launch_bounds__(256, 3)
__global__ void gemm_lse_kernel(const char* __restrict__ X4, const char* __restrict__ W4,
                                const unsigned* __restrict__ SX,
                                const unsigned* __restrict__ SW,
                                float* __restrict__ sumexp) {
  __shared__ char ldsA[2][BM * 64];   // [sub-step][row*64 + col]
  __shared__ char ldsB[2][BN * 64];

  const int tid  = threadIdx.x;
  const int lane = tid & 63;
  const int w    = tid >> 6;
  const int wm   = w >> 1;          // 2x2 wave grid, each wave 64x64
  const int wn   = w & 1;
  const int chunk   = blockIdx.x >> 6;
  const int rowtile = blockIdx.x & 63;
  const int nt0 = (chunk * NTILES) / NSPLIT;
  const int nt1 = ((chunk + 1) * NTILES) / NSPLIT;

  const int arow0 = rowtile * BM;
  const int rl = lane & 15;
  const int h  = lane >> 4;
  const int rcol = ((h ^ ((rl >> 1) & 3)) << 4);       // frag read col
  const int scol = (((lane & 3) ^ ((lane >> 3) & 3)) << 4);  // stage src col

  // staging geometry: per matrix, 4 items: sub ∈ {0,1} x k ∈ {0,1};
  // segq = w*2+k (8 segs of 1KB per sub-tile), row = segq*16 + lane>>2.
  int srowit[4], ssubit[4], sdstit[4];
#pragma unroll
  for (int it = 0; it < 4; ++it) {
    int sub = it >> 1, k = it & 1;
    int segq = w * 2 + k;
    srowit[it] = segq * 16 + (lane >> 2);
    ssubit[it] = sub;
    sdstit[it] = segq * 1024 + lane * 16;
  }
  // A source byte offsets (block-constant, + h2*128 at stage time)
  size_t aoff[4];
#pragma unroll
  for (int it = 0; it < 4; ++it)
    aoff[it] = (size_t)(arow0 + srowit[it]) * ROWB4 + ssubit[it] * 64 + scol;

  // A-scales for the whole block: 4 uints (bytes = ks 0..3)
  unsigned sa4[4];
#pragma unroll
  for (int mi = 0; mi < 4; ++mi)
    sa4[mi] = SX[(arow0 + wm * 64 + mi * 16 + rl) * 4 + h];

  float se[4][4];
#pragma unroll
  for (int mi = 0; mi < 4; ++mi)
#pragma unroll
    for (int r = 0; r < 4; ++r) se[mi][r] = 0.f;

  for (int nt = nt0; nt < nt1; ++nt) {
    const int brow0 = nt * BN;

    // B-scales for this nt (latency hides under stage drain)
    unsigned sb4[4];
#pragma unroll
    for (int ni = 0; ni < 4; ++ni)
      sb4[ni] = SW[(brow0 + wn * 64 + ni * 16 + rl) * 4 + h];

    size_t boff[4];
#pragma unroll
    for (int it = 0; it < 4; ++it)
      boff[it] = (size_t)(brow0 + srowit[it]) * ROWB4 + ssubit[it] * 64 + scol;

    f32x4 acc[4][4];
#pragma unroll
    for (int mi = 0; mi < 4; ++mi)
#pragma unroll
      for (int ni = 0; ni < 4; ++ni) {
        f32x4 z = {0.f, 0.f, 0.f, 0.f};
        acc[mi][ni] = z;
      }

#pragma unroll
    for (int h2 = 0; h2 < 2; ++h2) {
      __syncthreads();               // prev phase's LDS reads done
#pragma unroll
      for (int it = 0; it < 4; ++it)
        gll16(X4 + aoff[it] + h2 * 128, ldsA[ssubit[it]] + sdstit[it]);
#pragma unroll
      for (int it = 0; it < 4; ++it)
        gll16(W4 + boff[it] + h2 * 128, ldsB[ssubit[it]] + sdstit[it]);
      __syncthreads();               // staging drained (vmcnt 0)

#pragma unroll
      for (int ks2 = 0; ks2 < 2; ++ks2) {
        const int ks = h2 * 2 + ks2;
        uint4 aq[4], bq[4];
#pragma unroll
        for (int mi = 0; mi < 4; ++mi)
          aq[mi] = *(const uint4*)(ldsA[ks2] + (wm * 64 + mi * 16 + rl) * 64 + rcol);
#pragma unroll
        for (int ni = 0; ni < 4; ++ni)
          bq[ni] = *(const uint4*)(ldsB[ks2] + (wn * 64 + ni * 16 + rl) * 64 + rcol);

        int saks[4], sbks[4];
#pragma unroll
        for (int mi = 0; mi < 4; ++mi) saks[mi] = (int)((sa4[mi] >> (ks * 8)) & 0xFFu);
#pragma unroll
        for (int ni = 0; ni < 4; ++ni) sbks[ni] = (int)((sb4[ni] >> (ks * 8)) & 0xFFu);

        i32x8 bv[4];
#pragma unroll
        for (int ni = 0; ni < 4; ++ni) bv[ni] = mk8(bq[ni]);
#pragma unroll
        for (int mi = 0; mi < 4; ++mi) {
          i32x8 av = mk8(aq[mi]);
#pragma unroll
          for (int ni = 0; ni < 4; ++ni)
            acc[mi][ni] = __builtin_amdgcn_mfma_scale_f32_16x16x128_f8f6f4(
                av, bv[ni], acc[mi][ni],
                4, 4,                      // cbsz=FP4(A), blgp=FP4(B)
                0, saks[mi], 0, sbks[ni]);
        }
      }
    }

    // epilogue: sum exp over this 128-col tile (register-only)
    const int colb = nt * BN + wn * 64 + rl;
#pragma unroll
    for (int ni = 0; ni < 4; ++ni) {
      bool ok = (colb + ni * 16) < NUM_CLASS;
#pragma unroll
      for (int mi = 0; mi < 4; ++mi)
#pragma unroll
        for (int r = 0; r < 4; ++r)
          if (ok) se[mi][r] += __expf(acc[mi][ni][r]);
    }
  }

  // C/D layout: col = lane&15 (summed over), row = (lane>>4)*4 + r
#pragma unroll
  for (int m = 1; m < 16; m <<= 1)
#pragma unroll
    for (int mi = 0; mi < 4; ++mi)
#pragma unroll
      for (int r = 0; r < 4; ++r)
        se[mi][r] += __shfl_xor(se[mi][r], m);

  if ((lane & 15) == 0) {
#pragma unroll
    for (int mi = 0; mi < 4; ++mi)
#pragma unroll
      for (int r = 0; r < 4; ++r) {
        int grow = arow0 + wm * 64 + mi * 16 + ((lane >> 4) << 2) + r;
        atomicAdd(&sumexp[grow], se[mi][r]);
      }
  }
}

// ---- final scalar reduction ----
__global__ void finalize_kernel(const float* __restrict__ sumexp,
                                const float* __restrict__ tlogit,
                                const float* __restrict__ qrow,
                                float* __restrict__ out) {
  int tid = threadIdx.x;     // 1024 threads
  float acc = 0.f, q = 0.f;
  for (int i = tid; i < MROWS; i += 1024)
    acc += logf(sumexp[i]) - tlogit[i];
  for (int i = tid; i < BATCH; i += 1024)
    q += qrow[i];
#pragma unroll
  for (int m = 1; m < 64; m <<= 1) {
    acc += __shfl_xor(acc, m);
    q   += __shfl_xor(q, m);
  }
  __shared__ float redA[16], redQ[16];
  if ((tid & 63) == 0) { redA[tid >> 6] = acc; redQ[tid >> 6] = q; }
  __syncthreads();
  if (tid == 0) {
    float s = 0.f, qq = 0.f;
#pragma unroll
    for (int i = 0; i < 16; ++i) { s += redA[i]; qq += redQ[i]; }
    // loss = (ce1_sum + ce2_sum)/B + PARAM * 0.5 * qsum / B ; PARAM=0.5, B=4096
    out[0] = s * (1.0f / BATCH) + qq * (1.0f / 16384.0f);
  }
}

extern "C" void kernel_launch(void* const* d_in, const int* in_sizes, int n_in,
                              void* d_out, int out_size, void* d_ws, size_t ws_size,
                              hipStream_t stream) {
  const float* sx = (const float*)d_in[0];
  const float* hx = (const float*)d_in[1];
  const int*   tg = (const int*)d_in[2];
  const float* ct = (const float*)d_in[3];
  const float* wt = (const float*)d_in[4];
  float* out = (float*)d_out;

  char* ws = (char*)d_ws;
  char* X4 = ws;                                                // 2,097,152 B
  char* W4 = X4 + (size_t)MROWS * ROWB4;                        // 2,588,672 B
  unsigned char* SX = (unsigned char*)(W4 + (size_t)WPAD_ROWS * ROWB4); // 131,072 B
  unsigned char* SW = SX + (size_t)MROWS * KBLKS;               // 161,792 B
  char* tail = (char*)(SW + (size_t)WPAD_ROWS * KBLKS);
  float* sumexp = (float*)tail;                                 // 8192 f32
  float* tlogit = (float*)(tail + (size_t)MROWS * 4);           // 8192 f32
  float* qrow   = (float*)(tail + (size_t)MROWS * 8);           // 4096 f32

  prep_kernel<<<PB_TOTAL, 256, 0, stream>>>(sx, hx, tg, ct, wt,
                                            (uint4*)X4, (uint4*)W4, SX, SW,
                                            tlogit, qrow, (float4*)sumexp);
  gemm_lse_kernel<<<NSPLIT * ROWTILES, 256, 0, stream>>>(X4, W4,
                                                         (const unsigned*)SX,
                                                         (const unsigned*)SW, sumexp);
  finalize_kernel<<<1, 1024, 0, stream>>>(sumexp, tlogit, qrow, out);
}